// Round 1
// baseline (299.355 us; speedup 1.0000x reference)
//
#include <hip/hip_runtime.h>
#include <stdint.h>

typedef unsigned long long u64;

#define BATCH 16384
#define FEAT  1024
#define KW    16          // 1024 bits / 64 per row
#define NCLS  10

// ---- workspace layout (bytes) ----
// XA/XB ping-pong packed activations: 16384 * 16 * 8 = 2 MB each
#define OFF_XA   ((size_t)0)
#define OFF_XB   ((size_t)(2u * 1024u * 1024u))
#define OFF_WP1  ((size_t)(4u * 1024u * 1024u))          // 128 KB
#define OFF_WP2  (OFF_WP1 + (size_t)FEAT * KW * 8)
#define OFF_WP3  (OFF_WP2 + (size_t)FEAT * KW * 8)
#define OFF_WP4  (OFF_WP3 + (size_t)FEAT * KW * 8)       // 10*16*8 = 1280 B
#define OFF_TH   (OFF_WP4 + (size_t)2048)                 // 3*1024 int2 = 24 KB
// total ~4.75 MB of d_ws

// ---------------------------------------------------------------------------
// Pack sign bits: bit = (src[i] >= thr). 64 consecutive elements -> one u64.
// Grid must cover exactly n elements, n % 256 == 0.
__global__ void pack_bits_kernel(const float* __restrict__ src,
                                 u64* __restrict__ dst, float thr) {
    int i = blockIdx.x * 256 + threadIdx.x;
    bool bit = src[i] >= thr;
    u64 m = __ballot(bit);
    if ((threadIdx.x & 63) == 0) dst[i >> 6] = m;
}

// ---------------------------------------------------------------------------
// Per-column integer thresholds for BN+binarize.
// y = (h - m) * (g * rsqrt(v+1e-5)) + b >= 0
//   s>0:  h >= ceil(m - b/s)   (flip=0)
//   s<0:  h <= floor(m - b/s)  (flip=1)
// h is an integer, so integer compare is exact given a double threshold.
__global__ void bn_thresh_kernel(const float* __restrict__ g1, const float* __restrict__ b1,
                                 const float* __restrict__ m1, const float* __restrict__ v1,
                                 const float* __restrict__ g2, const float* __restrict__ b2,
                                 const float* __restrict__ m2, const float* __restrict__ v2,
                                 const float* __restrict__ g3, const float* __restrict__ b3,
                                 const float* __restrict__ m3, const float* __restrict__ v3,
                                 int2* __restrict__ out) {
    int gid = blockIdx.x * 256 + threadIdx.x;   // 0..3071
    int l = gid >> 10, j = gid & 1023;
    const float *g, *b, *m, *v;
    if (l == 0)      { g = g1; b = b1; m = m1; v = v1; }
    else if (l == 1) { g = g2; b = b2; m = m2; v = v2; }
    else             { g = g3; b = b3; m = m3; v = v3; }
    double gd = (double)g[j], bd = (double)b[j], md = (double)m[j], vd = (double)v[j];
    double s = gd / sqrt(vd + 1e-5);
    int ti, flip;
    if (s > 0.0)      { ti = (int)ceil(md - bd / s);  flip = 0; }
    else if (s < 0.0) { ti = (int)floor(md - bd / s); flip = 1; }
    else              { ti = (bd >= 0.0) ? -2000000 : 2000000; flip = 0; }
    out[gid] = make_int2(ti, flip);
}

// ---------------------------------------------------------------------------
// Binary GEMM layer: Xout[b][j] = bit( BN_j( 1024 - 2*popc(Xin[b] ^ Wp[j]) ) )
// Tile: 128 rows x 128 cols per 256-thread block; whole K (16 u64) in LDS.
// LDS word index XOR-swizzled by (row>>3)&15 so compute reads are conflict-free.
__global__ void __launch_bounds__(256)
gemm_bin_kernel(const u64* __restrict__ Xin, const u64* __restrict__ Wp,
                const int2* __restrict__ th, u64* __restrict__ Xout) {
    __shared__ u64 Xs[128][KW];
    __shared__ u64 Ws[128][KW];

    const int tid = threadIdx.x;
    const int bx = blockIdx.x & 7;    // col block (8 x 128 cols)
    const int by = blockIdx.x >> 3;   // row block (128 x 128 rows)

    const u64* Xg = Xin + (size_t)by * 128 * KW;   // contiguous 16 KB
    const u64* Wg = Wp + (size_t)bx * 128 * KW;    // contiguous 16 KB

    // Stage both tiles: 1024 ulong2 each, 4 per thread, fully coalesced.
#pragma unroll
    for (int i = 0; i < 4; ++i) {
        int idx = tid + i * 256;          // ulong2 index 0..1023
        int row = idx >> 3;
        int wp = (idx & 7) * 2;
        int swz = (row >> 3) & 15;
        ulonglong2 xv = ((const ulonglong2*)Xg)[idx];
        Xs[row][wp ^ swz] = xv.x;
        Xs[row][(wp + 1) ^ swz] = xv.y;
        ulonglong2 wv = ((const ulonglong2*)Wg)[idx];
        Ws[row][wp ^ swz] = wv.x;
        Ws[row][(wp + 1) ^ swz] = wv.y;
    }
    __syncthreads();

    const int tr = tid >> 4;    // 0..15 -> rows tr*8 .. tr*8+7   (row>>3 == tr)
    const int tc = tid & 15;    // 0..15 -> cols tc*8 .. tc*8+7   (col>>3 == tc)

    int acc[8][8];
#pragma unroll
    for (int i = 0; i < 8; ++i)
#pragma unroll
        for (int j = 0; j < 8; ++j) acc[i][j] = 0;

    const u64* xptr = &Xs[tr * 8][0];
    const u64* wptr = &Ws[tc * 8][0];

#pragma unroll 2
    for (int w = 0; w < KW; ++w) {
        int wt = w ^ tr;
        int wc = w ^ tc;
        u64 xw[8], wv[8];
#pragma unroll
        for (int i = 0; i < 8; ++i) xw[i] = xptr[i * KW + wt];
#pragma unroll
        for (int j = 0; j < 8; ++j) wv[j] = wptr[j * KW + wc];
#pragma unroll
        for (int i = 0; i < 8; ++i)
#pragma unroll
            for (int j = 0; j < 8; ++j)
                acc[i][j] += __builtin_popcountll(xw[i] ^ wv[j]);
    }

    // Thresholds for my 8 columns
    int2 t8[8];
#pragma unroll
    for (int j = 0; j < 8; ++j) t8[j] = th[bx * 128 + tc * 8 + j];

    __syncthreads();
    // Reuse Xs as a 128x16 byte tile: byte (row, tc) holds bits for cols tc*8..tc*8+7
    unsigned char* Bb = (unsigned char*)&Xs[0][0];
#pragma unroll
    for (int i = 0; i < 8; ++i) {
        unsigned int byte = 0;
#pragma unroll
        for (int j = 0; j < 8; ++j) {
            int h = 1024 - 2 * acc[i][j];
            int bit = t8[j].y ? (h <= t8[j].x) : (h >= t8[j].x);
            byte |= (unsigned int)bit << j;
        }
        Bb[(tr * 8 + i) * 16 + tc] = (unsigned char)byte;
    }
    __syncthreads();

    // Each thread emits one packed u64 (2 words per row of the 128-col tile)
    int lrow = tid >> 1, half = tid & 1;
    u64 word = *(const u64*)&Bb[lrow * 16 + half * 8];
    Xout[(size_t)(by * 128 + lrow) * KW + bx * 2 + half] = word;
}

// ---------------------------------------------------------------------------
// Final 1024 -> 10 binary matmul + TensorNorm affine (double, exact-ish).
__global__ void final_layer_kernel(const u64* __restrict__ X3, const u64* __restrict__ W4p,
                                   const float* __restrict__ tw, const float* __restrict__ tb,
                                   const float* __restrict__ tm, const float* __restrict__ tv,
                                   float* __restrict__ out) {
    int idx = blockIdx.x * 256 + threadIdx.x;
    if (idx >= BATCH * NCLS) return;
    int row = idx / NCLS;
    int c = idx - row * NCLS;
    const u64* xr = X3 + (size_t)row * KW;
    const u64* wr = W4p + (size_t)c * KW;
    int p = 0;
#pragma unroll
    for (int w = 0; w < KW; ++w) p += __builtin_popcountll(xr[w] ^ wr[w]);
    int h = 1024 - 2 * p;
    double rs = 1.0 / sqrt((double)tv[0] + 1e-4);
    double y = ((double)h - (double)tm[0]) * rs * (double)tw[0] + (double)tb[0];
    out[idx] = (float)y;
}

// ---------------------------------------------------------------------------
extern "C" void kernel_launch(void* const* d_in, const int* in_sizes, int n_in,
                              void* d_out, int out_size, void* d_ws, size_t ws_size,
                              hipStream_t stream) {
    const float* x  = (const float*)d_in[0];
    const float* W1 = (const float*)d_in[1];
    const float* W2 = (const float*)d_in[2];
    const float* W3 = (const float*)d_in[3];
    const float* W4 = (const float*)d_in[4];
    const float* g1 = (const float*)d_in[5];
    const float* b1 = (const float*)d_in[6];
    const float* m1 = (const float*)d_in[7];
    const float* v1 = (const float*)d_in[8];
    const float* g2 = (const float*)d_in[9];
    const float* b2 = (const float*)d_in[10];
    const float* m2 = (const float*)d_in[11];
    const float* v2 = (const float*)d_in[12];
    const float* g3 = (const float*)d_in[13];
    const float* b3 = (const float*)d_in[14];
    const float* m3 = (const float*)d_in[15];
    const float* v3 = (const float*)d_in[16];
    const float* tw = (const float*)d_in[17];
    const float* tb = (const float*)d_in[18];
    const float* tm = (const float*)d_in[19];
    const float* tv = (const float*)d_in[20];

    char* ws = (char*)d_ws;
    u64* XA  = (u64*)(ws + OFF_XA);
    u64* XB  = (u64*)(ws + OFF_XB);
    u64* Wp1 = (u64*)(ws + OFF_WP1);
    u64* Wp2 = (u64*)(ws + OFF_WP2);
    u64* Wp3 = (u64*)(ws + OFF_WP3);
    u64* Wp4 = (u64*)(ws + OFF_WP4);
    int2* TH = (int2*)(ws + OFF_TH);

    // 1) pack input sign bits (2x-1 >= 0  <=>  x >= 0.5) and weight sign bits
    pack_bits_kernel<<<(BATCH * FEAT) / 256, 256, 0, stream>>>(x, XA, 0.5f);
    pack_bits_kernel<<<(FEAT * FEAT) / 256, 256, 0, stream>>>(W1, Wp1, 0.0f);
    pack_bits_kernel<<<(FEAT * FEAT) / 256, 256, 0, stream>>>(W2, Wp2, 0.0f);
    pack_bits_kernel<<<(FEAT * FEAT) / 256, 256, 0, stream>>>(W3, Wp3, 0.0f);
    pack_bits_kernel<<<(NCLS * FEAT) / 256, 256, 0, stream>>>(W4, Wp4, 0.0f);

    // 2) BN thresholds for the 3 hidden layers
    bn_thresh_kernel<<<12, 256, 0, stream>>>(g1, b1, m1, v1, g2, b2, m2, v2,
                                             g3, b3, m3, v3, TH);

    // 3) three binary GEMM + threshold layers (ping-pong XA/XB)
    gemm_bin_kernel<<<1024, 256, 0, stream>>>(XA, Wp1, TH,        XB);
    gemm_bin_kernel<<<1024, 256, 0, stream>>>(XB, Wp2, TH + 1024, XA);
    gemm_bin_kernel<<<1024, 256, 0, stream>>>(XA, Wp3, TH + 2048, XB);

    // 4) final 1024->10 matmul + TensorNorm
    final_layer_kernel<<<(BATCH * NCLS + 255) / 256, 256, 0, stream>>>(
        XB, Wp4, tw, tb, tm, tv, (float*)d_out);
}